// Round 2
// baseline (3081.885 us; speedup 1.0000x reference)
//
#include <hip/hip_runtime.h>
#include <hip/hip_bf16.h>

// Problem constants (Mixtral attention prefill)
#define S_LEN 2048
#define HID 4096
#define NH 32
#define NKV 8
#define HD 128
#define NQKV 6144   // NH*HD + 2*NKV*HD

typedef unsigned short u16;
typedef unsigned int u32;
typedef __bf16 bf16x8 __attribute__((ext_vector_type(8)));
typedef float f32x4 __attribute__((ext_vector_type(4)));

__device__ __forceinline__ float bf2f(u16 u) {
    union { u32 i; float f; } x; x.i = ((u32)u) << 16; return x.f;
}
__device__ __forceinline__ u16 f2bf(float f) {
    union { float f; u32 i; } x; x.f = f;
    u32 r = x.i + 0x7fffu + ((x.i >> 16) & 1u);   // RNE
    return (u16)(r >> 16);
}
__device__ __forceinline__ u32 pack2(float a, float b) {
    return (u32)f2bf(a) | ((u32)f2bf(b) << 16);
}

// ---------------------------------------------------------------------------
// GEMM: C[M][N] = X[M][K] * W[N][K]^T, bf16 MFMA, fp32 accumulate.
// X is fp32 (converted during staging) or bf16 per XF32. W always fp32,
// rows [0,r1) from W0, [r1,r2) from W1, [r2,..) from W2 (fused QKV).
// 64x64 tile, BK=32, 4 waves; mfma_f32_16x16x32_bf16 with verified layouts:
// A lane: A[m=lane&15][k=(lane>>4)*8+j]; B lane: B[k=(lane>>4)*8+j][n=lane&15];
// D lane: col=lane&15, row=(lane>>4)*4+reg (learn_hip m89/m91).
// ---------------------------------------------------------------------------
template <bool XF32, bool OUTBF16>
__global__ __launch_bounds__(256) void gemm_bt(
    const void* __restrict__ Xv,
    const float* __restrict__ W0, int r1,
    const float* __restrict__ W1, int r2,
    const float* __restrict__ W2,
    void* __restrict__ C, int K, int ldc)
{
    __shared__ u16 Xs[64][48];   // 32 used + pad (row stride 96 B, 16B-aligned)
    __shared__ u16 Ws[64][48];

    const int tid  = threadIdx.x;
    const int w    = tid >> 6;
    const int lane = tid & 63;
    const int m0   = blockIdx.y * 64;
    const int n0   = blockIdx.x * 64;

    // staging: thread covers 8 k-elements (one 16B bf16 LDS store) per BK step
    const int sr = tid >> 2;          // tile row 0..63
    const int sc = (tid & 3) * 8;     // k offset 0,8,16,24

    const float* xrow32 = nullptr;
    const u16*   xrow16 = nullptr;
    if constexpr (XF32) xrow32 = (const float*)Xv + (size_t)(m0 + sr) * K;
    else                xrow16 = (const u16*)Xv + (size_t)(m0 + sr) * K;

    const int wr = n0 + sr;
    const float* wrow;
    if (wr < r1)      wrow = W0 + (size_t)wr * K;
    else if (wr < r2) wrow = W1 + (size_t)(wr - r1) * K;
    else              wrow = W2 + (size_t)(wr - r2) * K;

    f32x4 acc[4] = {};
    const int mrow = w * 16 + (lane & 15);
    const int nrow = lane & 15;
    const int kq   = (lane >> 4) * 8;

    for (int k0 = 0; k0 < K; k0 += 32) {
        __syncthreads();
        if constexpr (XF32) {
            float4 x0 = *reinterpret_cast<const float4*>(xrow32 + k0 + sc);
            float4 x1 = *reinterpret_cast<const float4*>(xrow32 + k0 + sc + 4);
            uint4 p;
            p.x = pack2(x0.x, x0.y); p.y = pack2(x0.z, x0.w);
            p.z = pack2(x1.x, x1.y); p.w = pack2(x1.z, x1.w);
            *reinterpret_cast<uint4*>(&Xs[sr][sc]) = p;
        } else {
            *reinterpret_cast<uint4*>(&Xs[sr][sc]) =
                *reinterpret_cast<const uint4*>(xrow16 + k0 + sc);
        }
        {
            float4 w0v = *reinterpret_cast<const float4*>(wrow + k0 + sc);
            float4 w1v = *reinterpret_cast<const float4*>(wrow + k0 + sc + 4);
            uint4 p;
            p.x = pack2(w0v.x, w0v.y); p.y = pack2(w0v.z, w0v.w);
            p.z = pack2(w1v.x, w1v.y); p.w = pack2(w1v.z, w1v.w);
            *reinterpret_cast<uint4*>(&Ws[sr][sc]) = p;
        }
        __syncthreads();
        bf16x8 a = *reinterpret_cast<const bf16x8*>(&Xs[mrow][kq]);
#pragma unroll
        for (int t = 0; t < 4; ++t) {
            bf16x8 b = *reinterpret_cast<const bf16x8*>(&Ws[t * 16 + nrow][kq]);
            acc[t] = __builtin_amdgcn_mfma_f32_16x16x32_bf16(a, b, acc[t], 0, 0, 0);
        }
    }

    const int mb = m0 + w * 16 + ((lane >> 4) << 2);
#pragma unroll
    for (int t = 0; t < 4; ++t) {
        const int col = n0 + t * 16 + (lane & 15);
#pragma unroll
        for (int i = 0; i < 4; ++i) {
            if constexpr (OUTBF16)
                ((u16*)C)[(size_t)(mb + i) * ldc + col] = f2bf(acc[t][i]);
            else
                ((float*)C)[(size_t)(mb + i) * ldc + col] = acc[t][i];
        }
    }
}

// ---------------------------------------------------------------------------
// RoPE (half-split, theta=1e6) on q,k; repack to head-major bf16.
// qkv bf16 [S][6144]; qb [NH][S][HD]; kb/vb [NKV][S][HD].
// ---------------------------------------------------------------------------
__global__ __launch_bounds__(256) void rope_kernel(
    const u16* __restrict__ qkv, const int* __restrict__ pos,
    u16* __restrict__ qb, u16* __restrict__ kb, u16* __restrict__ vb)
{
    const int n   = blockIdx.x;
    const int tid = threadIdx.x;
    __shared__ float cs[64], sn[64];
    if (tid < 64) {
        float p   = (float)pos[n];
        float inv = powf(1.0e6f, -(float)tid / 64.0f);
        float f   = p * inv;
        cs[tid] = cosf(f);
        sn[tid] = sinf(f);
    }
    __syncthreads();
    const u16* row = qkv + (size_t)n * NQKV;

    for (int i = tid; i < NH * 64; i += 256) {           // q: 32 heads x 64 pairs
        int h = i >> 6, j = i & 63;
        float x1 = bf2f(row[h * HD + j]), x2 = bf2f(row[h * HD + j + 64]);
        size_t base = ((size_t)h * S_LEN + n) * HD;
        qb[base + j]      = f2bf(x1 * cs[j] - x2 * sn[j]);
        qb[base + j + 64] = f2bf(x2 * cs[j] + x1 * sn[j]);
    }
    for (int i = tid; i < NKV * 64; i += 256) {          // k: 8 heads x 64 pairs
        int g = i >> 6, j = i & 63;
        const u16* kr = row + NH * HD + g * HD;
        float x1 = bf2f(kr[j]), x2 = bf2f(kr[j + 64]);
        size_t base = ((size_t)g * S_LEN + n) * HD;
        kb[base + j]      = f2bf(x1 * cs[j] - x2 * sn[j]);
        kb[base + j + 64] = f2bf(x2 * cs[j] + x1 * sn[j]);
    }
    for (int i = tid; i < NKV * HD; i += 256) {          // v: copy bf16
        int g = i >> 7, d = i & 127;
        vb[((size_t)g * S_LEN + n) * HD + d] = row[NH * HD + NKV * HD + g * HD + d];
    }
}

// ---------------------------------------------------------------------------
// Flash-style causal GQA attention, fp32 vector math.
// Block = (head h, 64 queries). 4 threads per query; thread owns interleaved
// dims d = part + 4*j (conflict-free LDS banks). K-tiles of 32 keys.
// ao [S][NH*HD] bf16 (token-major for the out-proj GEMM).
// ---------------------------------------------------------------------------
__global__ __launch_bounds__(256) void attn_kernel(
    const u16* __restrict__ qb, const u16* __restrict__ kb,
    const u16* __restrict__ vb, u16* __restrict__ ao)
{
    __shared__ float Ks[32][128];   // 16 KB
    __shared__ float Vs[32][128];   // 16 KB
    __shared__ float Ps[64][32];    //  8 KB  (40 KB total)

    const int tid  = threadIdx.x;
    const int h    = blockIdx.y;
    const int q0   = blockIdx.x * 64;
    const int g    = h >> 2;                 // kv group (M = NH/NKV = 4)
    const int qi   = tid >> 2;               // 0..63 local query
    const int part = tid & 3;                // dim quarter
    const float scale = 0.08838834764831845f; // 1/sqrt(128)

    float qr[32];
    {
        const u16* qsrc = qb + ((size_t)h * S_LEN + q0 + qi) * HD;
#pragma unroll
        for (int j = 0; j < 32; ++j) qr[j] = bf2f(qsrc[part + 4 * j]) * scale;
    }
    float m = -1e30f, l = 0.0f;
    float o[32];
#pragma unroll
    for (int j = 0; j < 32; ++j) o[j] = 0.0f;

    const int ntiles = (q0 >> 5) + 2;        // keys up to q0+63 inclusive
    for (int kt = 0; kt < ntiles; ++kt) {
        const int k0 = kt * 32;
        __syncthreads();
#pragma unroll
        for (int it = 0; it < 2; ++it) {
            int c = it * 256 + tid;          // 0..511
            int off = c * 8;
            int row = off >> 7, col = off & 127;
            uint4 ku = *reinterpret_cast<const uint4*>(
                kb + ((size_t)g * S_LEN + k0 + row) * HD + col);
            uint4 vu = *reinterpret_cast<const uint4*>(
                vb + ((size_t)g * S_LEN + k0 + row) * HD + col);
            const u32 kw[4] = {ku.x, ku.y, ku.z, ku.w};
            const u32 vw[4] = {vu.x, vu.y, vu.z, vu.w};
#pragma unroll
            for (int t = 0; t < 4; ++t) {
                Ks[row][col + 2 * t]     = bf2f((u16)(kw[t] & 0xffff));
                Ks[row][col + 2 * t + 1] = bf2f((u16)(kw[t] >> 16));
                Vs[row][col + 2 * t]     = bf2f((u16)(vw[t] & 0xffff));
                Vs[row][col + 2 * t + 1] = bf2f((u16)(vw[t] >> 16));
            }
        }
        __syncthreads();

        // phase A: scores (4-lane partial dot + shuffle reduce)
#pragma unroll 4
        for (int kk = 0; kk < 32; ++kk) {
            float s = 0.0f;
#pragma unroll
            for (int j = 0; j < 32; ++j) s += qr[j] * Ks[kk][part + 4 * j];
            s += __shfl_xor(s, 1);
            s += __shfl_xor(s, 2);
            if (k0 + kk > q0 + qi) s = -1e30f;
            if (part == 0) Ps[qi][kk] = s;
        }
        __syncthreads();

        // phase B: online softmax update (8 keys per part)
        {
            float tm = -1e30f;
#pragma unroll
            for (int ii = 0; ii < 8; ++ii)
                tm = fmaxf(tm, Ps[qi][part * 8 + ii]);
            tm = fmaxf(tm, __shfl_xor(tm, 1));
            tm = fmaxf(tm, __shfl_xor(tm, 2));
            float m_new = fmaxf(m, tm);
            float alpha = __expf(m - m_new);
            float lsum = 0.0f;
#pragma unroll
            for (int ii = 0; ii < 8; ++ii) {
                float p = __expf(Ps[qi][part * 8 + ii] - m_new);
                Ps[qi][part * 8 + ii] = p;
                lsum += p;
            }
            lsum += __shfl_xor(lsum, 1);
            lsum += __shfl_xor(lsum, 2);
            l = l * alpha + lsum;
            m = m_new;
#pragma unroll
            for (int j = 0; j < 32; ++j) o[j] *= alpha;
        }
        __syncthreads();

        // phase C: PV accumulate
#pragma unroll 4
        for (int kk = 0; kk < 32; ++kk) {
            float p = Ps[qi][kk];
#pragma unroll
            for (int j = 0; j < 32; ++j) o[j] += p * Vs[kk][part + 4 * j];
        }
    }

    const float invl = 1.0f / l;
    u16* dst = ao + (size_t)(q0 + qi) * (NH * HD) + h * HD;
#pragma unroll
    for (int j = 0; j < 32; ++j) dst[part + 4 * j] = f2bf(o[j] * invl);
}

// ---------------------------------------------------------------------------
// Workspace layout (bytes), total 64 MB:
//   qkv bf16 [2048][6144]   @ 0          (25,165,824)
//   qb  bf16 [32][2048][128]@ 25165824   (16,777,216)
//   kb  bf16 [8][2048][128] @ 41943040   ( 4,194,304)
//   vb  bf16 [8][2048][128] @ 46137344   ( 4,194,304)
//   ao  bf16 [2048][4096]   @ 50331648   (16,777,216)  -> end 67,108,864
// ---------------------------------------------------------------------------
extern "C" void kernel_launch(void* const* d_in, const int* in_sizes, int n_in,
                              void* d_out, int out_size, void* d_ws, size_t ws_size,
                              hipStream_t stream)
{
    const float* h   = (const float*)d_in[0];   // [2048][4096] fp32
    const int*   pos = (const int*)d_in[1];     // [2048] int32
    const float* wq  = (const float*)d_in[2];   // [4096][4096] fp32
    const float* wk  = (const float*)d_in[3];   // [1024][4096] fp32
    const float* wv  = (const float*)d_in[4];   // [1024][4096] fp32
    const float* wo  = (const float*)d_in[5];   // [4096][4096] fp32

    char* ws = (char*)d_ws;
    u16* qkv = (u16*)(ws);
    u16* qb  = (u16*)(ws + 25165824);
    u16* kb  = (u16*)(ws + 41943040);
    u16* vb  = (u16*)(ws + 46137344);
    u16* ao  = (u16*)(ws + 50331648);

    // 1) fused QKV projection: qkv[2048][6144] = h * [wq;wk;wv]^T  (bf16 out)
    dim3 g1(NQKV / 64, S_LEN / 64);
    gemm_bt<true, true><<<g1, 256, 0, stream>>>(
        h, wq, NH * HD, wk, NH * HD + NKV * HD, wv, qkv, HID, NQKV);
    // 2) RoPE + repack to head-major
    rope_kernel<<<S_LEN, 256, 0, stream>>>(qkv, pos, qb, kb, vb);
    // 3) causal GQA flash attention
    attn_kernel<<<dim3(S_LEN / 64, NH), 256, 0, stream>>>(qb, kb, vb, ao);
    // 4) output projection -> fp32 out
    dim3 g2(HID / 64, S_LEN / 64);
    gemm_bt<false, false><<<g2, 256, 0, stream>>>(
        ao, wo, HID, wo, HID, wo, d_out, NH * HD, HID);
}

// Round 3
// 892.685 us; speedup vs baseline: 3.4524x; 3.4524x over previous
//
#include <hip/hip_runtime.h>
#include <hip/hip_bf16.h>

// Problem constants (Mixtral attention prefill)
#define S_LEN 2048
#define HID 4096
#define NH 32
#define NKV 8
#define HD 128
#define NQKV 6144   // NH*HD + 2*NKV*HD

typedef unsigned short u16;
typedef unsigned int u32;
typedef __bf16 bf16x8 __attribute__((ext_vector_type(8)));
typedef float f32x4 __attribute__((ext_vector_type(4)));

__device__ __forceinline__ float bf2f(u16 u) {
    union { u32 i; float f; } x; x.i = ((u32)u) << 16; return x.f;
}
__device__ __forceinline__ u16 f2bf(float f) {
    union { float f; u32 i; } x; x.f = f;
    u32 r = x.i + 0x7fffu + ((x.i >> 16) & 1u);   // RNE
    return (u16)(r >> 16);
}
__device__ __forceinline__ u32 pack2(float a, float b) {
    return (u32)f2bf(a) | ((u32)f2bf(b) << 16);
}

// ---------------------------------------------------------------------------
// GEMM: C[M][N] = X[M][K] * W[N][K]^T, bf16 MFMA, fp32 accumulate.
// (unchanged from R2 — known-good; GEMM upgrade is next round's target)
// ---------------------------------------------------------------------------
template <bool XF32, bool OUTBF16>
__global__ __launch_bounds__(256) void gemm_bt(
    const void* __restrict__ Xv,
    const float* __restrict__ W0, int r1,
    const float* __restrict__ W1, int r2,
    const float* __restrict__ W2,
    void* __restrict__ C, int K, int ldc)
{
    __shared__ u16 Xs[64][48];
    __shared__ u16 Ws[64][48];

    const int tid  = threadIdx.x;
    const int w    = tid >> 6;
    const int lane = tid & 63;
    const int m0   = blockIdx.y * 64;
    const int n0   = blockIdx.x * 64;

    const int sr = tid >> 2;
    const int sc = (tid & 3) * 8;

    const float* xrow32 = nullptr;
    const u16*   xrow16 = nullptr;
    if constexpr (XF32) xrow32 = (const float*)Xv + (size_t)(m0 + sr) * K;
    else                xrow16 = (const u16*)Xv + (size_t)(m0 + sr) * K;

    const int wr = n0 + sr;
    const float* wrow;
    if (wr < r1)      wrow = W0 + (size_t)wr * K;
    else if (wr < r2) wrow = W1 + (size_t)(wr - r1) * K;
    else              wrow = W2 + (size_t)(wr - r2) * K;

    f32x4 acc[4] = {};
    const int mrow = w * 16 + (lane & 15);
    const int nrow = lane & 15;
    const int kq   = (lane >> 4) * 8;

    for (int k0 = 0; k0 < K; k0 += 32) {
        __syncthreads();
        if constexpr (XF32) {
            float4 x0 = *reinterpret_cast<const float4*>(xrow32 + k0 + sc);
            float4 x1 = *reinterpret_cast<const float4*>(xrow32 + k0 + sc + 4);
            uint4 p;
            p.x = pack2(x0.x, x0.y); p.y = pack2(x0.z, x0.w);
            p.z = pack2(x1.x, x1.y); p.w = pack2(x1.z, x1.w);
            *reinterpret_cast<uint4*>(&Xs[sr][sc]) = p;
        } else {
            *reinterpret_cast<uint4*>(&Xs[sr][sc]) =
                *reinterpret_cast<const uint4*>(xrow16 + k0 + sc);
        }
        {
            float4 w0v = *reinterpret_cast<const float4*>(wrow + k0 + sc);
            float4 w1v = *reinterpret_cast<const float4*>(wrow + k0 + sc + 4);
            uint4 p;
            p.x = pack2(w0v.x, w0v.y); p.y = pack2(w0v.z, w0v.w);
            p.z = pack2(w1v.x, w1v.y); p.w = pack2(w1v.z, w1v.w);
            *reinterpret_cast<uint4*>(&Ws[sr][sc]) = p;
        }
        __syncthreads();
        bf16x8 a = *reinterpret_cast<const bf16x8*>(&Xs[mrow][kq]);
#pragma unroll
        for (int t = 0; t < 4; ++t) {
            bf16x8 b = *reinterpret_cast<const bf16x8*>(&Ws[t * 16 + nrow][kq]);
            acc[t] = __builtin_amdgcn_mfma_f32_16x16x32_bf16(a, b, acc[t], 0, 0, 0);
        }
    }

    const int mb = m0 + w * 16 + ((lane >> 4) << 2);
#pragma unroll
    for (int t = 0; t < 4; ++t) {
        const int col = n0 + t * 16 + (lane & 15);
#pragma unroll
        for (int i = 0; i < 4; ++i) {
            if constexpr (OUTBF16)
                ((u16*)C)[(size_t)(mb + i) * ldc + col] = f2bf(acc[t][i]);
            else
                ((float*)C)[(size_t)(mb + i) * ldc + col] = acc[t][i];
        }
    }
}

// ---------------------------------------------------------------------------
// RoPE (half-split, theta=1e6) on q,k; repack to head-major bf16.
// Q is pre-scaled by 1/sqrt(HD) here (folded into RoPE, free) so the
// attention kernel's MFMA scores need no extra multiply.
// ---------------------------------------------------------------------------
__global__ __launch_bounds__(256) void rope_kernel(
    const u16* __restrict__ qkv, const int* __restrict__ pos,
    u16* __restrict__ qb, u16* __restrict__ kb, u16* __restrict__ vb)
{
    const int n   = blockIdx.x;
    const int tid = threadIdx.x;
    const float scale = 0.08838834764831845f; // 1/sqrt(128)
    __shared__ float cs[64], sn[64];
    if (tid < 64) {
        float p   = (float)pos[n];
        float inv = powf(1.0e6f, -(float)tid / 64.0f);
        float f   = p * inv;
        cs[tid] = cosf(f);
        sn[tid] = sinf(f);
    }
    __syncthreads();
    const u16* row = qkv + (size_t)n * NQKV;

    for (int i = tid; i < NH * 64; i += 256) {           // q (scaled)
        int h = i >> 6, j = i & 63;
        float x1 = bf2f(row[h * HD + j]), x2 = bf2f(row[h * HD + j + 64]);
        size_t base = ((size_t)h * S_LEN + n) * HD;
        qb[base + j]      = f2bf((x1 * cs[j] - x2 * sn[j]) * scale);
        qb[base + j + 64] = f2bf((x2 * cs[j] + x1 * sn[j]) * scale);
    }
    for (int i = tid; i < NKV * 64; i += 256) {          // k
        int g = i >> 6, j = i & 63;
        const u16* kr = row + NH * HD + g * HD;
        float x1 = bf2f(kr[j]), x2 = bf2f(kr[j + 64]);
        size_t base = ((size_t)g * S_LEN + n) * HD;
        kb[base + j]      = f2bf(x1 * cs[j] - x2 * sn[j]);
        kb[base + j + 64] = f2bf(x2 * cs[j] + x1 * sn[j]);
    }
    for (int i = tid; i < NKV * HD; i += 256) {          // v copy
        int g = i >> 7, d = i & 127;
        vb[((size_t)g * S_LEN + n) * HD + d] = row[NH * HD + NKV * HD + g * HD + d];
    }
}

// ---------------------------------------------------------------------------
// MFMA flash attention (causal GQA). Block = (head, 64 queries), 4 waves x
// 16 queries. K-tile = 64 keys. mfma_f32_16x16x32_bf16 verified layouts:
//   A lane(quad=lane>>4, m=lane&15): A[m][quad*8+j]
//   B lane(quad, n=lane&15):         B[quad*8+j][n]
//   C/D lane: col=lane&15, row=quad*4+reg
// QK^T: A=Q (m=query,k=dim), B=K^T (row-major K tile, 8 contig dims/lane).
// PV:   A=P (m=query,k=key; LDS round-trip C->A layout), B=V (transposed
//       V tile in LDS so 8 contig keys/lane).
// LDS strides padded (136/72/72 u16) for 16B-aligned rows + bank spread.
// ---------------------------------------------------------------------------
__global__ __launch_bounds__(256) void attn_mfma(
    const u16* __restrict__ qb, const u16* __restrict__ kb,
    const u16* __restrict__ vb, u16* __restrict__ ao)
{
    __shared__ u16 Ks[64][136];    // 17408 B  key-major
    __shared__ u16 Vt[128][72];    // 18432 B  dim-major (V transposed)
    __shared__ u16 Ps[4][16][72];  //  9216 B  per-wave P tile

    const int tid  = threadIdx.x;
    const int w    = tid >> 6;
    const int lane = tid & 63;
    const int quad = lane >> 4;
    const int n16  = lane & 15;
    const int h    = blockIdx.y;
    const int g    = h >> 2;
    const int q0   = blockIdx.x * 64;

    // Q A-fragments (qb pre-scaled by 1/sqrt(HD) in rope)
    bf16x8 qf[4];
    {
        const u16* qrow = qb + ((size_t)h * S_LEN + q0 + w * 16 + n16) * HD;
#pragma unroll
        for (int s = 0; s < 4; ++s)
            qf[s] = *reinterpret_cast<const bf16x8*>(qrow + s * 32 + quad * 8);
    }

    f32x4 of[8] = {};
    float mrow[4], lrow[4];
#pragma unroll
    for (int r = 0; r < 4; ++r) { mrow[r] = -1e30f; lrow[r] = 0.0f; }

    const int ntiles = (q0 >> 6) + 1;
    for (int kt = 0; kt < ntiles; ++kt) {
        const int k0 = kt * 64;
        __syncthreads();
        // ---- stage K tile (coalesced, b128 LDS writes) ----
#pragma unroll
        for (int i = 0; i < 4; ++i) {
            int chunk = tid + 256 * i;
            int key = chunk >> 4, d0 = (chunk & 15) * 8;
            *reinterpret_cast<uint4*>(&Ks[key][d0]) =
                *reinterpret_cast<const uint4*>(
                    kb + ((size_t)g * S_LEN + k0 + key) * HD + d0);
        }
        // ---- stage V transposed (per-wave uniform dim-row -> 2-way max) ----
        {
            int key = tid & 63;
            const u16* vrow = vb + ((size_t)g * S_LEN + k0 + key) * HD;
#pragma unroll
            for (int i = 0; i < 4; ++i) {
                int d0 = (tid >> 6) * 8 + i * 32;
                uint4 vv = *reinterpret_cast<const uint4*>(vrow + d0);
                const u32 vw[4] = {vv.x, vv.y, vv.z, vv.w};
#pragma unroll
                for (int t = 0; t < 4; ++t) {
                    Vt[d0 + 2 * t][key]     = (u16)(vw[t] & 0xffff);
                    Vt[d0 + 2 * t + 1][key] = (u16)(vw[t] >> 16);
                }
            }
        }
        __syncthreads();

        // ---- QK^T: 16 MFMA -> scores for 16 queries x 64 keys ----
        f32x4 sc[4] = {};
#pragma unroll
        for (int s = 0; s < 4; ++s) {
#pragma unroll
            for (int t = 0; t < 4; ++t) {
                bf16x8 bf = *reinterpret_cast<const bf16x8*>(
                    &Ks[t * 16 + n16][s * 32 + quad * 8]);
                sc[t] = __builtin_amdgcn_mfma_f32_16x16x32_bf16(qf[s], bf, sc[t], 0, 0, 0);
            }
        }

        // ---- causal mask (only the diagonal tile needs it) ----
        if (kt == ntiles - 1) {
            const int qbase = q0 + w * 16 + quad * 4;
#pragma unroll
            for (int t = 0; t < 4; ++t) {
                int key = k0 + t * 16 + n16;
#pragma unroll
                for (int r = 0; r < 4; ++r)
                    if (key > qbase + r) sc[t][r] = -1e30f;
            }
        }

        // ---- online softmax (per query row = quad*4+r), P -> LDS bf16 ----
#pragma unroll
        for (int r = 0; r < 4; ++r) {
            float mx = fmaxf(fmaxf(sc[0][r], sc[1][r]), fmaxf(sc[2][r], sc[3][r]));
            mx = fmaxf(mx, __shfl_xor(mx, 1));
            mx = fmaxf(mx, __shfl_xor(mx, 2));
            mx = fmaxf(mx, __shfl_xor(mx, 4));
            mx = fmaxf(mx, __shfl_xor(mx, 8));
            float mnew  = fmaxf(mrow[r], mx);
            float alpha = __expf(mrow[r] - mnew);
            float ls = 0.0f;
#pragma unroll
            for (int t = 0; t < 4; ++t) {
                float p = __expf(sc[t][r] - mnew);
                Ps[w][quad * 4 + r][t * 16 + n16] = f2bf(p);
                ls += p;
            }
            ls += __shfl_xor(ls, 1);
            ls += __shfl_xor(ls, 2);
            ls += __shfl_xor(ls, 4);
            ls += __shfl_xor(ls, 8);
            lrow[r] = lrow[r] * alpha + ls;
            mrow[r] = mnew;
#pragma unroll
            for (int nt = 0; nt < 8; ++nt) of[nt][r] *= alpha;
        }
        __threadfence_block();   // order P writes before A-frag reads (same wave)

        // ---- PV: 16 MFMA, accumulate O (16 queries x 128 dims) ----
#pragma unroll
        for (int s = 0; s < 2; ++s) {
            bf16x8 af = *reinterpret_cast<const bf16x8*>(
                &Ps[w][n16][s * 32 + quad * 8]);
#pragma unroll
            for (int nt = 0; nt < 8; ++nt) {
                bf16x8 bf = *reinterpret_cast<const bf16x8*>(
                    &Vt[nt * 16 + n16][s * 32 + quad * 8]);
                of[nt] = __builtin_amdgcn_mfma_f32_16x16x32_bf16(af, bf, of[nt], 0, 0, 0);
            }
        }
    }

    // ---- epilogue: normalize, write ao[token][h*128+dim] ----
#pragma unroll
    for (int r = 0; r < 4; ++r) {
        float inv = 1.0f / lrow[r];
        u16* dst = ao + (size_t)(q0 + w * 16 + quad * 4 + r) * (NH * HD) + h * HD + n16;
#pragma unroll
        for (int nt = 0; nt < 8; ++nt)
            dst[nt * 16] = f2bf(of[nt][r] * inv);
    }
}

// ---------------------------------------------------------------------------
// Workspace layout (bytes), total 64 MB:
//   qkv bf16 [2048][6144]   @ 0          (25,165,824)
//   qb  bf16 [32][2048][128]@ 25165824   (16,777,216)
//   kb  bf16 [8][2048][128] @ 41943040   ( 4,194,304)
//   vb  bf16 [8][2048][128] @ 46137344   ( 4,194,304)
//   ao  bf16 [2048][4096]   @ 50331648   (16,777,216)  -> end 67,108,864
// ---------------------------------------------------------------------------
extern "C" void kernel_launch(void* const* d_in, const int* in_sizes, int n_in,
                              void* d_out, int out_size, void* d_ws, size_t ws_size,
                              hipStream_t stream)
{
    const float* h   = (const float*)d_in[0];
    const int*   pos = (const int*)d_in[1];
    const float* wq  = (const float*)d_in[2];
    const float* wk  = (const float*)d_in[3];
    const float* wv  = (const float*)d_in[4];
    const float* wo  = (const float*)d_in[5];

    char* ws = (char*)d_ws;
    u16* qkv = (u16*)(ws);
    u16* qb  = (u16*)(ws + 25165824);
    u16* kb  = (u16*)(ws + 41943040);
    u16* vb  = (u16*)(ws + 46137344);
    u16* ao  = (u16*)(ws + 50331648);

    dim3 g1(NQKV / 64, S_LEN / 64);
    gemm_bt<true, true><<<g1, 256, 0, stream>>>(
        h, wq, NH * HD, wk, NH * HD + NKV * HD, wv, qkv, HID, NQKV);
    rope_kernel<<<S_LEN, 256, 0, stream>>>(qkv, pos, qb, kb, vb);
    attn_mfma<<<dim3(S_LEN / 64, NH), 256, 0, stream>>>(qb, kb, vb, ao);
    dim3 g2(HID / 64, S_LEN / 64);
    gemm_bt<false, false><<<g2, 256, 0, stream>>>(
        ao, wo, HID, wo, HID, wo, d_out, NH * HD, HID);
}

// Round 4
// 700.006 us; speedup vs baseline: 4.4027x; 1.2753x over previous
//
#include <hip/hip_runtime.h>
#include <hip/hip_bf16.h>

// Problem constants (Mixtral attention prefill)
#define S_LEN 2048
#define HID 4096
#define NH 32
#define NKV 8
#define HD 128
#define NQKV 6144   // NH*HD + 2*NKV*HD

typedef unsigned short u16;
typedef unsigned int u32;
typedef __bf16 bf16x8 __attribute__((ext_vector_type(8)));
typedef float f32x4 __attribute__((ext_vector_type(4)));

__device__ __forceinline__ float bf2f(u16 u) {
    union { u32 i; float f; } x; x.i = ((u32)u) << 16; return x.f;
}
__device__ __forceinline__ u16 f2bf(float f) {
    union { float f; u32 i; } x; x.f = f;
    u32 r = x.i + 0x7fffu + ((x.i >> 16) & 1u);   // RNE
    return (u16)(r >> 16);
}
__device__ __forceinline__ u32 pack2(float a, float b) {
    return (u32)f2bf(a) | ((u32)f2bf(b) << 16);
}
// async global->LDS, 16 B per lane; LDS dest is wave-uniform base + lane*16
__device__ __forceinline__ void gld16(const u16* g, u16* l) {
    __builtin_amdgcn_global_load_lds(
        (const __attribute__((address_space(1))) u32*)g,
        (__attribute__((address_space(3))) u32*)l, 16, 0, 0);
}

// ---------------------------------------------------------------------------
// fp32 -> bf16 convert (8 elems/thread), n8 = n/8
// ---------------------------------------------------------------------------
__global__ __launch_bounds__(256) void cvt_f32_bf16(
    const float* __restrict__ src, u16* __restrict__ dst, int n8)
{
    int i = blockIdx.x * 256 + threadIdx.x;
    if (i >= n8) return;
    const float4* s = (const float4*)src + (size_t)i * 2;
    float4 x0 = s[0], x1 = s[1];
    uint4 p;
    p.x = pack2(x0.x, x0.y); p.y = pack2(x0.z, x0.w);
    p.z = pack2(x1.x, x1.y); p.w = pack2(x1.z, x1.w);
    *((uint4*)dst + i) = p;
}

// ---------------------------------------------------------------------------
// m97-style GEMM: C[M][N] = X[M][K] * W[N][K]^T, all bf16, fp32 acc.
// 128x128 tile, BK=32, 4 waves in 2x2; 4x4 16x16 C-tiles per wave.
// Staging via global_load_lds width=16 (contiguous LDS, no padding).
// ---------------------------------------------------------------------------
template <bool OUTBF16>
__global__ __launch_bounds__(256) void gemm128(
    const u16* __restrict__ X, const u16* __restrict__ W,
    void* __restrict__ C, int K, int ldc)
{
    __shared__ __align__(16) u16 As[128 * 32];   // 8 KB
    __shared__ __align__(16) u16 Bs[128 * 32];   // 8 KB

    const int tid  = threadIdx.x;
    const int w    = tid >> 6;
    const int lane = tid & 63;
    const int quad = lane >> 4;
    const int n16  = lane & 15;
    const int m0   = blockIdx.y * 128;
    const int n0   = blockIdx.x * 128;
    const int wr   = (w >> 1) * 64;
    const int wc   = (w & 1) * 64;

    const int c0 = tid;          // staging chunk ids: row=c>>2, koff=(c&3)*8
    const int c1 = tid + 256;

    f32x4 acc[4][4] = {};

    for (int k0 = 0; k0 < K; k0 += 32) {
        __syncthreads();
        // A tile: 128 rows x 32 k (8 KB) in 512 16B chunks
        gld16(X + (size_t)(m0 + (c0 >> 2)) * K + k0 + (c0 & 3) * 8,
              As + (size_t)(w * 64) * 8);
        gld16(X + (size_t)(m0 + (c1 >> 2)) * K + k0 + (c1 & 3) * 8,
              As + (size_t)(256 + w * 64) * 8);
        // B tile
        gld16(W + (size_t)(n0 + (c0 >> 2)) * K + k0 + (c0 & 3) * 8,
              Bs + (size_t)(w * 64) * 8);
        gld16(W + (size_t)(n0 + (c1 >> 2)) * K + k0 + (c1 & 3) * 8,
              Bs + (size_t)(256 + w * 64) * 8);
        __syncthreads();

        bf16x8 a[4], b[4];
#pragma unroll
        for (int t = 0; t < 4; ++t) {
            a[t] = *reinterpret_cast<const bf16x8*>(As + (wr + t * 16 + n16) * 32 + quad * 8);
            b[t] = *reinterpret_cast<const bf16x8*>(Bs + (wc + t * 16 + n16) * 32 + quad * 8);
        }
#pragma unroll
        for (int mt = 0; mt < 4; ++mt)
#pragma unroll
            for (int nt = 0; nt < 4; ++nt)
                acc[mt][nt] = __builtin_amdgcn_mfma_f32_16x16x32_bf16(
                    a[mt], b[nt], acc[mt][nt], 0, 0, 0);
    }

#pragma unroll
    for (int mt = 0; mt < 4; ++mt) {
        const int row0 = m0 + wr + mt * 16 + quad * 4;
#pragma unroll
        for (int nt = 0; nt < 4; ++nt) {
            const int col = n0 + wc + nt * 16 + n16;
#pragma unroll
            for (int r = 0; r < 4; ++r) {
                if constexpr (OUTBF16)
                    ((u16*)C)[(size_t)(row0 + r) * ldc + col] = f2bf(acc[mt][nt][r]);
                else
                    ((float*)C)[(size_t)(row0 + r) * ldc + col] = acc[mt][nt][r];
            }
        }
    }
}

// ---------------------------------------------------------------------------
// Fallback GEMM (R3): fp32 inputs converted on the fly, 64x64 tile.
// ---------------------------------------------------------------------------
template <bool XF32, bool OUTBF16>
__global__ __launch_bounds__(256) void gemm_bt(
    const void* __restrict__ Xv,
    const float* __restrict__ W0, int r1,
    const float* __restrict__ W1, int r2,
    const float* __restrict__ W2,
    void* __restrict__ C, int K, int ldc)
{
    __shared__ u16 Xs[64][48];
    __shared__ u16 Ws[64][48];

    const int tid  = threadIdx.x;
    const int w    = tid >> 6;
    const int lane = tid & 63;
    const int m0   = blockIdx.y * 64;
    const int n0   = blockIdx.x * 64;

    const int sr = tid >> 2;
    const int sc = (tid & 3) * 8;

    const float* xrow32 = nullptr;
    const u16*   xrow16 = nullptr;
    if constexpr (XF32) xrow32 = (const float*)Xv + (size_t)(m0 + sr) * K;
    else                xrow16 = (const u16*)Xv + (size_t)(m0 + sr) * K;

    const int wr = n0 + sr;
    const float* wrow;
    if (wr < r1)      wrow = W0 + (size_t)wr * K;
    else if (wr < r2) wrow = W1 + (size_t)(wr - r1) * K;
    else              wrow = W2 + (size_t)(wr - r2) * K;

    f32x4 acc[4] = {};
    const int mrow = w * 16 + (lane & 15);
    const int nrow = lane & 15;
    const int kq   = (lane >> 4) * 8;

    for (int k0 = 0; k0 < K; k0 += 32) {
        __syncthreads();
        if constexpr (XF32) {
            float4 x0 = *reinterpret_cast<const float4*>(xrow32 + k0 + sc);
            float4 x1 = *reinterpret_cast<const float4*>(xrow32 + k0 + sc + 4);
            uint4 p;
            p.x = pack2(x0.x, x0.y); p.y = pack2(x0.z, x0.w);
            p.z = pack2(x1.x, x1.y); p.w = pack2(x1.z, x1.w);
            *reinterpret_cast<uint4*>(&Xs[sr][sc]) = p;
        } else {
            *reinterpret_cast<uint4*>(&Xs[sr][sc]) =
                *reinterpret_cast<const uint4*>(xrow16 + k0 + sc);
        }
        {
            float4 w0v = *reinterpret_cast<const float4*>(wrow + k0 + sc);
            float4 w1v = *reinterpret_cast<const float4*>(wrow + k0 + sc + 4);
            uint4 p;
            p.x = pack2(w0v.x, w0v.y); p.y = pack2(w0v.z, w0v.w);
            p.z = pack2(w1v.x, w1v.y); p.w = pack2(w1v.z, w1v.w);
            *reinterpret_cast<uint4*>(&Ws[sr][sc]) = p;
        }
        __syncthreads();
        bf16x8 a = *reinterpret_cast<const bf16x8*>(&Xs[mrow][kq]);
#pragma unroll
        for (int t = 0; t < 4; ++t) {
            bf16x8 b = *reinterpret_cast<const bf16x8*>(&Ws[t * 16 + nrow][kq]);
            acc[t] = __builtin_amdgcn_mfma_f32_16x16x32_bf16(a, b, acc[t], 0, 0, 0);
        }
    }

    const int mb = m0 + w * 16 + ((lane >> 4) << 2);
#pragma unroll
    for (int t = 0; t < 4; ++t) {
        const int col = n0 + t * 16 + (lane & 15);
#pragma unroll
        for (int i = 0; i < 4; ++i) {
            if constexpr (OUTBF16)
                ((u16*)C)[(size_t)(mb + i) * ldc + col] = f2bf(acc[t][i]);
            else
                ((float*)C)[(size_t)(mb + i) * ldc + col] = acc[t][i];
        }
    }
}

// ---------------------------------------------------------------------------
// RoPE (half-split, theta=1e6); Q pre-scaled by 1/sqrt(HD).
// ---------------------------------------------------------------------------
__global__ __launch_bounds__(256) void rope_kernel(
    const u16* __restrict__ qkv, const int* __restrict__ pos,
    u16* __restrict__ qb, u16* __restrict__ kb, u16* __restrict__ vb)
{
    const int n   = blockIdx.x;
    const int tid = threadIdx.x;
    const float scale = 0.08838834764831845f;
    __shared__ float cs[64], sn[64];
    if (tid < 64) {
        float p   = (float)pos[n];
        float inv = powf(1.0e6f, -(float)tid / 64.0f);
        float f   = p * inv;
        cs[tid] = cosf(f);
        sn[tid] = sinf(f);
    }
    __syncthreads();
    const u16* row = qkv + (size_t)n * NQKV;

    for (int i = tid; i < NH * 64; i += 256) {
        int h = i >> 6, j = i & 63;
        float x1 = bf2f(row[h * HD + j]), x2 = bf2f(row[h * HD + j + 64]);
        size_t base = ((size_t)h * S_LEN + n) * HD;
        qb[base + j]      = f2bf((x1 * cs[j] - x2 * sn[j]) * scale);
        qb[base + j + 64] = f2bf((x2 * cs[j] + x1 * sn[j]) * scale);
    }
    for (int i = tid; i < NKV * 64; i += 256) {
        int g = i >> 6, j = i & 63;
        const u16* kr = row + NH * HD + g * HD;
        float x1 = bf2f(kr[j]), x2 = bf2f(kr[j + 64]);
        size_t base = ((size_t)g * S_LEN + n) * HD;
        kb[base + j]      = f2bf(x1 * cs[j] - x2 * sn[j]);
        kb[base + j + 64] = f2bf(x2 * cs[j] + x1 * sn[j]);
    }
    for (int i = tid; i < NKV * HD; i += 256) {
        int g = i >> 7, d = i & 127;
        vb[((size_t)g * S_LEN + n) * HD + d] = row[NH * HD + NKV * HD + g * HD + d];
    }
}

// ---------------------------------------------------------------------------
// MFMA flash attention (causal GQA) — unchanged from R3 (passed, ~260 us).
// ---------------------------------------------------------------------------
__global__ __launch_bounds__(256) void attn_mfma(
    const u16* __restrict__ qb, const u16* __restrict__ kb,
    const u16* __restrict__ vb, u16* __restrict__ ao)
{
    __shared__ u16 Ks[64][136];
    __shared__ u16 Vt[128][72];
    __shared__ u16 Ps[4][16][72];

    const int tid  = threadIdx.x;
    const int w    = tid >> 6;
    const int lane = tid & 63;
    const int quad = lane >> 4;
    const int n16  = lane & 15;
    const int h    = blockIdx.y;
    const int g    = h >> 2;
    const int q0   = blockIdx.x * 64;

    bf16x8 qf[4];
    {
        const u16* qrow = qb + ((size_t)h * S_LEN + q0 + w * 16 + n16) * HD;
#pragma unroll
        for (int s = 0; s < 4; ++s)
            qf[s] = *reinterpret_cast<const bf16x8*>(qrow + s * 32 + quad * 8);
    }

    f32x4 of[8] = {};
    float mrow[4], lrow[4];
#pragma unroll
    for (int r = 0; r < 4; ++r) { mrow[r] = -1e30f; lrow[r] = 0.0f; }

    const int ntiles = (q0 >> 6) + 1;
    for (int kt = 0; kt < ntiles; ++kt) {
        const int k0 = kt * 64;
        __syncthreads();
#pragma unroll
        for (int i = 0; i < 4; ++i) {
            int chunk = tid + 256 * i;
            int key = chunk >> 4, d0 = (chunk & 15) * 8;
            *reinterpret_cast<uint4*>(&Ks[key][d0]) =
                *reinterpret_cast<const uint4*>(
                    kb + ((size_t)g * S_LEN + k0 + key) * HD + d0);
        }
        {
            int key = tid & 63;
            const u16* vrow = vb + ((size_t)g * S_LEN + k0 + key) * HD;
#pragma unroll
            for (int i = 0; i < 4; ++i) {
                int d0 = (tid >> 6) * 8 + i * 32;
                uint4 vv = *reinterpret_cast<const uint4*>(vrow + d0);
                const u32 vw[4] = {vv.x, vv.y, vv.z, vv.w};
#pragma unroll
                for (int t = 0; t < 4; ++t) {
                    Vt[d0 + 2 * t][key]     = (u16)(vw[t] & 0xffff);
                    Vt[d0 + 2 * t + 1][key] = (u16)(vw[t] >> 16);
                }
            }
        }
        __syncthreads();

        f32x4 sc[4] = {};
#pragma unroll
        for (int s = 0; s < 4; ++s) {
#pragma unroll
            for (int t = 0; t < 4; ++t) {
                bf16x8 bf = *reinterpret_cast<const bf16x8*>(
                    &Ks[t * 16 + n16][s * 32 + quad * 8]);
                sc[t] = __builtin_amdgcn_mfma_f32_16x16x32_bf16(qf[s], bf, sc[t], 0, 0, 0);
            }
        }

        if (kt == ntiles - 1) {
            const int qbase = q0 + w * 16 + quad * 4;
#pragma unroll
            for (int t = 0; t < 4; ++t) {
                int key = k0 + t * 16 + n16;
#pragma unroll
                for (int r = 0; r < 4; ++r)
                    if (key > qbase + r) sc[t][r] = -1e30f;
            }
        }

#pragma unroll
        for (int r = 0; r < 4; ++r) {
            float mx = fmaxf(fmaxf(sc[0][r], sc[1][r]), fmaxf(sc[2][r], sc[3][r]));
            mx = fmaxf(mx, __shfl_xor(mx, 1));
            mx = fmaxf(mx, __shfl_xor(mx, 2));
            mx = fmaxf(mx, __shfl_xor(mx, 4));
            mx = fmaxf(mx, __shfl_xor(mx, 8));
            float mnew  = fmaxf(mrow[r], mx);
            float alpha = __expf(mrow[r] - mnew);
            float ls = 0.0f;
#pragma unroll
            for (int t = 0; t < 4; ++t) {
                float p = __expf(sc[t][r] - mnew);
                Ps[w][quad * 4 + r][t * 16 + n16] = f2bf(p);
                ls += p;
            }
            ls += __shfl_xor(ls, 1);
            ls += __shfl_xor(ls, 2);
            ls += __shfl_xor(ls, 4);
            ls += __shfl_xor(ls, 8);
            lrow[r] = lrow[r] * alpha + ls;
            mrow[r] = mnew;
#pragma unroll
            for (int nt = 0; nt < 8; ++nt) of[nt][r] *= alpha;
        }
        __threadfence_block();

#pragma unroll
        for (int s = 0; s < 2; ++s) {
            bf16x8 af = *reinterpret_cast<const bf16x8*>(
                &Ps[w][n16][s * 32 + quad * 8]);
#pragma unroll
            for (int nt = 0; nt < 8; ++nt) {
                bf16x8 bf = *reinterpret_cast<const bf16x8*>(
                    &Vt[nt * 16 + n16][s * 32 + quad * 8]);
                of[nt] = __builtin_amdgcn_mfma_f32_16x16x32_bf16(af, bf, of[nt], 0, 0, 0);
            }
        }
    }

#pragma unroll
    for (int r = 0; r < 4; ++r) {
        float inv = 1.0f / lrow[r];
        u16* dst = ao + (size_t)(q0 + w * 16 + quad * 4 + r) * (NH * HD) + h * HD + n16;
#pragma unroll
        for (int nt = 0; nt < 8; ++nt)
            dst[nt * 16] = f2bf(of[nt][r] * inv);
    }
}

// ---------------------------------------------------------------------------
// Fast-path workspace overlay (bytes), peak 92,274,688:
//   hb   [2048][4096] bf16 @ 0           (16.8M)  -> reused as qb after gemm1
//   wqkv [6144][4096] bf16 @ 16,777,216  (50.3M)  -> dead after gemm1:
//        ao @ 16,777,216 (16.8M) | kb @ 33,554,432 | vb @ 37,748,736
//   wo_b [4096][4096] bf16 @ 41,943,040  (33.5M)  (converted after rope;
//        overlays wqkv tail + qkv head, both dead by then)
//   qkv  [2048][6144] bf16 @ 67,108,864  (25.2M)  -> dead after rope
// ---------------------------------------------------------------------------
extern "C" void kernel_launch(void* const* d_in, const int* in_sizes, int n_in,
                              void* d_out, int out_size, void* d_ws, size_t ws_size,
                              hipStream_t stream)
{
    const float* h   = (const float*)d_in[0];
    const int*   pos = (const int*)d_in[1];
    const float* wq  = (const float*)d_in[2];
    const float* wk  = (const float*)d_in[3];
    const float* wv  = (const float*)d_in[4];
    const float* wo  = (const float*)d_in[5];

    char* ws = (char*)d_ws;

    if (ws_size >= 92274688ull) {
        // ---- fast path: bf16 weight pre-convert + 128-tile global_load_lds GEMM
        u16* hb     = (u16*)(ws);
        u16* wqkv_b = (u16*)(ws + 16777216);
        u16* ao     = (u16*)(ws + 16777216);
        u16* kb     = (u16*)(ws + 33554432);
        u16* vb     = (u16*)(ws + 37748736);
        u16* wo_b   = (u16*)(ws + 41943040);
        u16* qkv    = (u16*)(ws + 67108864);
        u16* qb     = hb;

        cvt_f32_bf16<<<4096, 256, 0, stream>>>(h, hb, 1048576);          // 8.4M elems
        cvt_f32_bf16<<<8192, 256, 0, stream>>>(wq, wqkv_b, 2097152);     // 16.8M
        cvt_f32_bf16<<<2048, 256, 0, stream>>>(wk, wqkv_b + 16777216, 524288);
        cvt_f32_bf16<<<2048, 256, 0, stream>>>(wv, wqkv_b + 20971520, 524288);

        gemm128<true><<<dim3(NQKV / 128, S_LEN / 128), 256, 0, stream>>>(
            hb, wqkv_b, qkv, HID, NQKV);
        rope_kernel<<<S_LEN, 256, 0, stream>>>(qkv, pos, qb, kb, vb);
        cvt_f32_bf16<<<8192, 256, 0, stream>>>(wo, wo_b, 2097152);       // 16.8M
        attn_mfma<<<dim3(S_LEN / 64, NH), 256, 0, stream>>>(qb, kb, vb, ao);
        gemm128<false><<<dim3(HID / 128, S_LEN / 128), 256, 0, stream>>>(
            ao, wo_b, d_out, NH * HD, HID);
    } else {
        // ---- fallback (R3 layout, 64 MB)
        u16* qkv = (u16*)(ws);
        u16* qb  = (u16*)(ws + 25165824);
        u16* kb  = (u16*)(ws + 41943040);
        u16* vb  = (u16*)(ws + 46137344);
        u16* ao  = (u16*)(ws + 50331648);

        dim3 g1(NQKV / 64, S_LEN / 64);
        gemm_bt<true, true><<<g1, 256, 0, stream>>>(
            h, wq, NH * HD, wk, NH * HD + NKV * HD, wv, qkv, HID, NQKV);
        rope_kernel<<<S_LEN, 256, 0, stream>>>(qkv, pos, qb, kb, vb);
        attn_mfma<<<dim3(S_LEN / 64, NH), 256, 0, stream>>>(qb, kb, vb, ao);
        dim3 g2(HID / 64, S_LEN / 64);
        gemm_bt<false, false><<<g2, 256, 0, stream>>>(
            ao, wo, HID, wo, HID, wo, d_out, NH * HD, HID);
    }
}